// Round 10
// baseline (358.084 us; speedup 1.0000x reference)
//
#include <hip/hip_runtime.h>

// ---------- types ----------
typedef __attribute__((ext_vector_type(8))) _Float16 half8;
typedef __attribute__((ext_vector_type(2))) __fp16 half2r;   // cvt_pkrtz return type
typedef __attribute__((ext_vector_type(4))) float f32x4;

#define AS1 __attribute__((address_space(1)))
#define AS3 __attribute__((address_space(3)))

union H2U { half2r h; unsigned int u; };
union Frag { half8 v; unsigned long long d[2]; };

__device__ __forceinline__ unsigned int pk(float a, float b) {
    H2U x; x.h = __builtin_amdgcn_cvt_pkrtz(a, b); return x.u;
}

__device__ __forceinline__ void gload_lds16(const void* g, void* l) {
    __builtin_amdgcn_global_load_lds((const AS1 unsigned int*)g,
                                     (AS3 unsigned int*)l, 16, 0, 0);
}

// ---------- problem constants ----------
// M = B*T = 32768, D_STATE = 1088, D_MODEL = 1024, D_LATENT = 128
// W1 layout: panel-tile 16 KB blocks at ((p*17 + t) << 14); within a block,
// row r, k-in-tile kt: byte = (r<<7) + ((((kh<<2)|u) ^ (r&7)) << 4) + pos8
//   (kh=kt>>5, u=(kt&15)>>2, pos8=((kt&31)>>4)<<3) — one MFMA frag = one 16-B
// slot, oct-conflict-free for wave64 b128 reads (R8-verified).
// A is NO LONGER MATERIALIZED: gemm_read_f reg-loads S+w per K-tile, adds,
// cvt_pkrtz, and ds_writes the SAME packed-frag image directly into LDS.
#define WS2_OFF 2228224        // = 1024 rows * 2176 B  (W1 total size)
#define W2_ROWB 256            // kv weights: 2-slab 128-B layout

// pick the fused-add source for 64-f32 slab ks (0..16); ks is loop-uniform
__device__ __forceinline__ void pick_w(int ks, const float* wsp, const float* whp,
                                       const float* whs, const float* wtg,
                                       const float*& wbase, int& wstr, int& wko) {
    if (ks < 8)       { wbase = wsp; wstr = 512; wko = ks * 64; }
    else if (ks < 12) { wbase = whp; wstr = 256; wko = ks * 64 - 512; }
    else if (ks < 16) { wbase = whs; wstr = 256; wko = ks * 64 - 768; }
    else              { wbase = wtg; wstr = 64;  wko = 0; }
}

// packed-frag address within a 16-KB panel-tile block
__device__ __forceinline__ int pf_addr(int r, int kt) {
    int kh = kt >> 5, k32 = kt & 31;
    int u = (k32 & 15) >> 2, pos8 = (k32 >> 4) << 3;
    return (r << 7) + (((((kh << 2) | u) ^ (r & 7))) << 4) + pos8;
}

// ============ prologue: convert weights to f16 (R8-identical) ============
__global__ __launch_bounds__(256) void prep_w(const float* __restrict__ Wr,
                                              const float* __restrict__ Wk,
                                              const float* __restrict__ Wv,
                                              char* __restrict__ ws) {
    int id = blockIdx.x * 256 + threadIdx.x;
    if (id < 272 * 1024) {                       // W_read: 1024 x 1088, packed-frag
        int n = id / 272;
        int k = (id % 272) * 4;
        f32x4 w = *(const f32x4*)(Wr + (size_t)n * 1088 + k);
        uint2 q; q.x = pk(w.x, w.y); q.y = pk(w.z, w.w);
        int t = k >> 6;
        size_t off = ((size_t)((n >> 7) * 17 + t) << 14) + pf_addr(n & 127, k & 63);
        *(uint2*)(ws + off) = q;
    } else {                                     // Wk|Wv combined: 2048 x 128
        int j = id - 272 * 1024;
        int r = j >> 5;                          // 0..2047
        int k = (j & 31) << 2;                   // 0..124
        const float* src = (r < 1024) ? (Wk + (size_t)r * 128 + k)
                                      : (Wv + (size_t)(r - 1024) * 128 + k);
        f32x4 w = *(const f32x4*)src;
        uint2 q; q.x = pk(w.x, w.y); q.y = pk(w.z, w.w);
        size_t off = WS2_OFF + (size_t)r * W2_ROWB + ((k >> 6) << 7)
                   + (((k & 63) << 1) ^ ((r & 7) << 4));
        *(uint2*)(ws + off) = q;
    }
}

// ============ GEMM1 (fused): out = cvt(S + w) @ W_read^T ============
// BM=BN=256, BK=64, 8 waves (2M x 4N), wave tile 128x64, 2 x 64 KB LDS dbuf.
// Per tile t: issue 16 f32x4 reg-loads of S/w for t+1 (T14 issue-early) +
// 4 gload_lds for B(t+1); counted vmcnt(20) retires B(t) while 20 newer ops
// fly across the barrier; one compute section (64 MFMA, compiler-scheduled
// ds_read interleave); then add+cvt+ds_write A(t+1) into the next buffer.
// 2 barriers/tile. No a16 intermediate: saves 142 MB HBM + a whole pass.
__global__ __launch_bounds__(512, 2)
void gemm_read_f(const float* __restrict__ S, const float* __restrict__ wsp,
                 const float* __restrict__ whp, const float* __restrict__ whs,
                 const float* __restrict__ wtg, const char* __restrict__ wws,
                 float* __restrict__ out) {
    extern __shared__ char lds[];                // 131072 B

    int bid = blockIdx.x;
    int wg   = (bid & 7) * 64 + (bid >> 3);      // bijective XCD swizzle (512%8==0)
    int mblk = wg >> 2, nblk = wg & 3;
    int m0 = mblk << 8, n0 = nblk << 8;

    int tid = threadIdx.x;
    int lane = tid & 63, wid = tid >> 6;
    int wm = (wid >> 2) << 7, wn = (wid & 3) << 6;   // wave tile: 128x64
    int lp = lane & 15, lg = lane >> 4;

    int aoff = (wid >> 2) * 16384;               // wave's A-half region
    int boff = 32768 + (wn >> 7) * 16384;        // wave's B-half region
    int cb64 = wn & 64;                          // col base within B-half

    // B sources: 16-KB panel-tile blocks
    const char* srcB0 = wws + ((size_t)((n0 >> 7) * 17) << 14);
    const char* srcB1 = srcB0 + (17 << 14);

    // A-staging unit mapping: thread covers rows rbase+c*32 (c=0..7) at fixed
    // k4 column. Wave-instr = 4 rows x 16 lanes x 16 B = 256 B/row contiguous.
    int rbase = tid >> 4;                        // 0..31
    int k4 = (tid & 15) << 2;                    // 0..60

    f32x4 sreg[8], wreg[8];
    f32x4 acc[8][4] = {};
    Frag af[4], bf[4];

#define ALOAD(T) do {                                                      \
        const float* wbase; int wstr, wko;                                 \
        pick_w((T), wsp, whp, whs, wtg, wbase, wstr, wko);                 \
        _Pragma("unroll")                                                  \
        for (int c = 0; c < 8; ++c) {                                      \
            int row = m0 + rbase + c * 32;                                 \
            sreg[c] = *(const f32x4*)(S + (size_t)row * 1088 + (T) * 64 + k4); \
            wreg[c] = *(const f32x4*)(wbase + (size_t)row * wstr + wko + k4);  \
        }                                                                  \
    } while (0)

#define AWRITE(DB) do {                                                    \
        _Pragma("unroll")                                                  \
        for (int c = 0; c < 8; ++c) {                                      \
            int row = rbase + c * 32;                                      \
            uint2 q;                                                       \
            q.x = pk(sreg[c].x + wreg[c].x, sreg[c].y + wreg[c].y);        \
            q.y = pk(sreg[c].z + wreg[c].z, sreg[c].w + wreg[c].w);        \
            *(uint2*)(lds + (DB) + ((row >> 7) << 14)                      \
                      + pf_addr(row & 127, k4)) = q;                       \
        }                                                                  \
    } while (0)

#define BSTAGE(T, DB) do {                                                 \
        const char* s0_ = srcB0 + ((size_t)(T) << 14);                     \
        const char* s1_ = srcB1 + ((size_t)(T) << 14);                     \
        gload_lds16(s0_ + tid * 16,        lds + (DB) + 32768 + tid * 16); \
        gload_lds16(s0_ + 8192 + tid * 16, lds + (DB) + 40960 + tid * 16); \
        gload_lds16(s1_ + tid * 16,        lds + (DB) + 49152 + tid * 16); \
        gload_lds16(s1_ + 8192 + tid * 16, lds + (DB) + 57344 + tid * 16); \
    } while (0)

#define LOADA(MH, KH, BB) do {                                             \
        _Pragma("unroll")                                                  \
        for (int f = 0; f < 4; ++f) {                                      \
            int r_ = (MH) * 64 + f * 16 + lp;                              \
            af[f] = *(const Frag*)(lds + (BB) + aoff + (r_ << 7)           \
                     + ((((((KH) << 2) | lg) ^ (r_ & 7))) << 4));          \
        }                                                                  \
    } while (0)

#define LOADB(KH, BB) do {                                                 \
        _Pragma("unroll")                                                  \
        for (int g = 0; g < 4; ++g) {                                      \
            int c_ = cb64 + g * 16 + lp;                                   \
            bf[g] = *(const Frag*)(lds + (BB) + boff + (c_ << 7)           \
                     + ((((((KH) << 2) | lg) ^ (c_ & 7))) << 4));          \
        }                                                                  \
    } while (0)

#define MFMA16(MH) do {                                                    \
        __builtin_amdgcn_s_setprio(1);                                     \
        _Pragma("unroll")                                                  \
        for (int f = 0; f < 4; ++f)                                        \
            _Pragma("unroll")                                              \
            for (int g = 0; g < 4; ++g)                                    \
                acc[(MH) * 4 + f][g] = __builtin_amdgcn_mfma_f32_16x16x32_f16( \
                    af[f].v, bf[g].v, acc[(MH) * 4 + f][g], 0, 0, 0);      \
        __builtin_amdgcn_s_setprio(0);                                     \
    } while (0)

    // ---- prologue: tile 0 -> buf 0 (A via regs+ds_write, B via gload_lds)
    ALOAD(0);
    BSTAGE(0, 0);
    AWRITE(0);                                   // compiler waits sreg/wreg here
    asm volatile("s_waitcnt lgkmcnt(0)" ::: "memory");
    __builtin_amdgcn_s_barrier();                // A(0) visible; B(0) still flying

    for (int t = 0; t < 17; ++t) {
        int BB = (t & 1) << 16;
        int NB = BB ^ 65536;
        if (t < 16) {
            ALOAD(t + 1);                        // 16 reg loads, consumed at tile end
            BSTAGE(t + 1, NB);                   // 4 direct-to-LDS loads
            // retire everything older than {A(t+1):16, B(t+1):4} => B(t) landed
            asm volatile("s_waitcnt vmcnt(20)" ::: "memory");
        } else {
            asm volatile("s_waitcnt vmcnt(0)" ::: "memory");
        }
        __builtin_amdgcn_s_barrier();            // all waves: tile t fully in BB

        LOADB(0, BB); LOADA(0, 0, BB); MFMA16(0);
        LOADA(1, 0, BB);               MFMA16(1);
        LOADB(1, BB); LOADA(0, 1, BB); MFMA16(0);
        LOADA(1, 1, BB);               MFMA16(1);

        if (t < 16) {
            // A(t+1) regs ready (4 newest = B(t+1) may keep flying)
            asm volatile("s_waitcnt vmcnt(4)" ::: "memory");
            AWRITE(NB);
            asm volatile("s_waitcnt lgkmcnt(0)" ::: "memory");
        }
        __builtin_amdgcn_s_barrier();            // A(t+1) visible to all waves
    }

    // ---- epilogue: C[row = m0+wm+i*16+lg*4+r][col = n0+wn+j*16+lp]
    #pragma unroll
    for (int i = 0; i < 8; ++i)
        #pragma unroll
        for (int j = 0; j < 4; ++j) {
            int row = m0 + wm + i * 16 + (lg << 2);
            int col = n0 + wn + j * 16 + lp;
            float* p = out + (size_t)row * 1024 + col;
            #pragma unroll
            for (int r = 0; r < 4; ++r) p[(size_t)r * 1024] = acc[i][j][r];
        }
#undef ALOAD
#undef AWRITE
#undef BSTAGE
#undef LOADA
#undef LOADB
#undef MFMA16
}

// ============ GEMM2: k = latent@Wk^T, v = latent@Wv^T (R0-identical) ====
__global__ __launch_bounds__(256, 2)
void gemm_kv(const float* __restrict__ lat, const char* __restrict__ ws2,
             float* __restrict__ outk, float* __restrict__ outv) {
    __shared__ char lds[32768];
    char* Al = lds;
    char* Bl = lds + 16384;

    int bid = blockIdx.x;
    int wg   = (bid & 7) * 512 + (bid >> 3);     // 4096 % 8 == 0
    int mblk = wg >> 4, nb = wg & 15;
    int m0 = mblk << 7;
    int nrow0 = nb << 7;                          // row in combined Wk|Wv
    float* out = (nb < 8) ? outk : outv;
    int n0 = (nb & 7) << 7;

    int tid = threadIdx.x;
    int lane = tid & 63, wid = tid >> 6;
    int wm = (wid >> 1) << 6, wn = (wid & 1) << 6;
    int lp = lane & 15, lg = lane >> 4;

    f32x4 acc[4][4] = {};

    for (int ks = 0; ks < 2; ++ks) {
        __syncthreads();
        {
            const char* wrow = ws2 + (size_t)nrow0 * W2_ROWB + ks * 128;
            #pragma unroll
            for (int c = 0; c < 4; ++c) {
                int s = c * 4096 + wid * 1024 + lane * 16;
                int n = s >> 7, cb = s & 127;
                gload_lds16(wrow + (size_t)n * W2_ROWB + cb,
                            Bl + c * 4096 + wid * 1024);
            }
        }
        #pragma unroll
        for (int i = 0; i < 8; ++i) {
            int u = i * 256 + tid;
            int row = u >> 4;
            int k4 = (u & 15) << 2;
            f32x4 s4 = *(const f32x4*)(lat + (size_t)(m0 + row) * 128 + ks * 64 + k4);
            uint2 q; q.x = pk(s4.x, s4.y); q.y = pk(s4.z, s4.w);
            *(uint2*)(Al + (row << 7) + ((k4 << 1) ^ ((row & 7) << 4))) = q;
        }
        __syncthreads();

        #pragma unroll
        for (int b = 0; b < 2; ++b) {
            Frag af[4], bf[4];
            #pragma unroll
            for (int f = 0; f < 4; ++f) {
                int ra = wm + f * 16 + lp;  int xa = (ra & 7) << 4;
                af[f].d[0] = *(const unsigned long long*)(Al + (ra << 7) + ((b * 64 + lg * 8) ^ xa));
                af[f].d[1] = *(const unsigned long long*)(Al + (ra << 7) + ((b * 64 + 32 + lg * 8) ^ xa));
                int rb = wn + f * 16 + lp;  int xb = (rb & 7) << 4;
                bf[f].d[0] = *(const unsigned long long*)(Bl + (rb << 7) + ((b * 64 + lg * 8) ^ xb));
                bf[f].d[1] = *(const unsigned long long*)(Bl + (rb << 7) + ((b * 64 + 32 + lg * 8) ^ xb));
            }
            #pragma unroll
            for (int i = 0; i < 4; ++i)
                #pragma unroll
                for (int j = 0; j < 4; ++j)
                    acc[i][j] = __builtin_amdgcn_mfma_f32_16x16x32_f16(af[i].v, bf[j].v, acc[i][j], 0, 0, 0);
        }
    }

    #pragma unroll
    for (int i = 0; i < 4; ++i)
        #pragma unroll
        for (int j = 0; j < 4; ++j) {
            int row = m0 + wm + i * 16 + (lg << 2);
            int col = n0 + wn + j * 16 + lp;
            float* p = out + (size_t)row * 1024 + col;
            #pragma unroll
            for (int r = 0; r < 4; ++r) p[(size_t)r * 1024] = acc[i][j][r];
        }
}

// ============ host ============
extern "C" void kernel_launch(void* const* d_in, const int* in_sizes, int n_in,
                              void* d_out, int out_size, void* d_ws, size_t ws_size,
                              hipStream_t stream) {
    const float* S   = (const float*)d_in[0];
    const float* wsp = (const float*)d_in[1];
    const float* whp = (const float*)d_in[2];
    const float* whs = (const float*)d_in[3];
    const float* wtg = (const float*)d_in[4];
    const float* Wr  = (const float*)d_in[5];
    // d_in[6] = cache: fully overwritten by latent -> dead input
    const float* lat = (const float*)d_in[7];
    const float* Wk  = (const float*)d_in[8];
    const float* Wv  = (const float*)d_in[9];
    float* out = (float*)d_out;
    char*  ws  = (char*)d_ws;

    float* outk = out + 33554432ull;
    float* outv = out + 67108864ull;

    static bool lds_init = false;
    if (!lds_init) {
        hipFuncSetAttribute(reinterpret_cast<const void*>(gemm_read_f),
                            hipFuncAttributeMaxDynamicSharedMemorySize, 131072);
        lds_init = true;
    }

    // 3 launches; no a16 intermediate at all.
    hipLaunchKernelGGL(prep_w, dim3(1344), dim3(256), 0, stream, Wr, Wk, Wv, ws);
    hipLaunchKernelGGL(gemm_read_f, dim3(512), dim3(512), 131072, stream,
                       S, wsp, whp, whs, wtg, ws, out);
    hipLaunchKernelGGL(gemm_kv, dim3(4096), dim3(256), 0, stream,
                       lat, ws + WS2_OFF, outk, outv);
}

// Round 11
// 236.740 us; speedup vs baseline: 1.5126x; 1.5126x over previous
//
#include <hip/hip_runtime.h>

// ---------- types ----------
typedef __attribute__((ext_vector_type(8))) _Float16 half8;
typedef __attribute__((ext_vector_type(2))) __fp16 half2r;   // cvt_pkrtz return type
typedef __attribute__((ext_vector_type(4))) float f32x4;

#define AS1 __attribute__((address_space(1)))
#define AS3 __attribute__((address_space(3)))

union H2U { half2r h; unsigned int u; };
union Frag { half8 v; unsigned long long d[2]; };

__device__ __forceinline__ unsigned int pk(float a, float b) {
    H2U x; x.h = __builtin_amdgcn_cvt_pkrtz(a, b); return x.u;
}

__device__ __forceinline__ void gload_lds16(const void* g, void* l) {
    __builtin_amdgcn_global_load_lds((const AS1 unsigned int*)g,
                                     (AS3 unsigned int*)l, 16, 0, 0);
}

// ---------- problem constants ----------
// M = B*T = 32768, D_STATE = 1088, D_MODEL = 1024, D_LATENT = 128
// a16 / W1 layout: panel-tile 16 KB blocks at ((p*17 + t) << 14); within:
//   byte = (r<<7) + ((((kh<<2)|u) ^ (r&7)) << 4) + pos8   (R8-verified,
//   oct-conflict-free wave64 b128 frag reads; one MFMA frag = one 16-B slot)
#define WS2_OFF 2228224        // = 1024 rows * 2176 B  (W1 total size)
#define WS2_SZ  524288         // 2048 rows * 256 B
#define W2_ROWB 256            // kv weights: 2-slab 128-B layout
#define A16_SZ  71303168ull    // 32768 * 2176

// pick the fused-add source for 64-f32 slab ks (0..16)
__device__ __forceinline__ void pick_w(int ks, const float* wsp, const float* whp,
                                       const float* whs, const float* wtg,
                                       const float*& wbase, int& wstr, int& wko) {
    if (ks < 8)       { wbase = wsp; wstr = 512; wko = ks * 64; }
    else if (ks < 12) { wbase = whp; wstr = 256; wko = ks * 64 - 512; }
    else if (ks < 16) { wbase = whs; wstr = 256; wko = ks * 64 - 768; }
    else              { wbase = wtg; wstr = 64;  wko = 0; }
}

// packed-frag address within a 16-KB panel-tile block
__device__ __forceinline__ size_t pf_addr(int r, int kt) {
    int kh = kt >> 5, k32 = kt & 31;
    int u = (k32 & 15) >> 2, pos8 = (k32 >> 4) << 3;
    return ((size_t)r << 7) + ((size_t)((((kh << 2) | u) ^ (r & 7)) << 4)) + pos8;
}

// ============ prologue: convert weights to f16 (R8-identical) ============
__global__ __launch_bounds__(256) void prep_w(const float* __restrict__ Wr,
                                              const float* __restrict__ Wk,
                                              const float* __restrict__ Wv,
                                              char* __restrict__ ws) {
    int id = blockIdx.x * 256 + threadIdx.x;
    if (id < 272 * 1024) {                       // W_read: 1024 x 1088, packed-frag
        int n = id / 272;
        int k = (id % 272) * 4;
        f32x4 w = *(const f32x4*)(Wr + (size_t)n * 1088 + k);
        uint2 q; q.x = pk(w.x, w.y); q.y = pk(w.z, w.w);
        int t = k >> 6;
        size_t off = ((size_t)((n >> 7) * 17 + t) << 14) + pf_addr(n & 127, k & 63);
        *(uint2*)(ws + off) = q;
    } else {                                     // Wk|Wv combined: 2048 x 128
        int j = id - 272 * 1024;
        int r = j >> 5;                          // 0..2047
        int k = (j & 31) << 2;                   // 0..124
        const float* src = (r < 1024) ? (Wk + (size_t)r * 128 + k)
                                      : (Wv + (size_t)(r - 1024) * 128 + k);
        f32x4 w = *(const f32x4*)src;
        uint2 q; q.x = pk(w.x, w.y); q.y = pk(w.z, w.w);
        size_t off = WS2_OFF + (size_t)r * W2_ROWB + ((k >> 6) << 7)
                   + (((k & 63) << 1) ^ ((r & 7) << 4));
        *(uint2*)(ws + off) = q;
    }
}

// ---------- fuse_a body (R9-identical) ----------
__device__ __forceinline__
void fuse_body(int u, const float* __restrict__ S, const float* __restrict__ wsp,
               const float* __restrict__ whp, const float* __restrict__ whs,
               const float* __restrict__ wtg, char* __restrict__ a16) {
    int row = u / 272;
    int rem = u % 272;
    int ks = rem >> 4;
    int k4 = (rem & 15) << 2;

    const float* wbase; int wstr, wko;
    pick_w(ks, wsp, whp, whs, wtg, wbase, wstr, wko);

    f32x4 s4 = *(const f32x4*)(S + (size_t)row * 1088 + ks * 64 + k4);
    f32x4 w4 = *(const f32x4*)(wbase + (size_t)row * wstr + wko + k4);
    uint2 q; q.x = pk(s4.x + w4.x, s4.y + w4.y);
             q.y = pk(s4.z + w4.z, s4.w + w4.w);
    size_t off = ((size_t)((row >> 7) * 17 + ks) << 14) + pf_addr(row & 127, k4);
    *(uint2*)(a16 + off) = q;
}

// ---------- kv body (R9-identical) ----------
__device__ __forceinline__
void kv_body(int mblk, int nb, const float* __restrict__ lat,
             const char* __restrict__ ws2, float* __restrict__ outk,
             float* __restrict__ outv, char* lds) {
    char* Al = lds;
    char* Bl = lds + 16384;

    int m0 = mblk << 7;
    int nrow0 = nb << 7;
    float* out = (nb < 8) ? outk : outv;
    int n0 = (nb & 7) << 7;

    int tid = threadIdx.x;
    int lane = tid & 63, wid = tid >> 6;
    int wm = (wid >> 1) << 6, wn = (wid & 1) << 6;
    int lp = lane & 15, lg = lane >> 4;

    f32x4 acc[4][4] = {};

    for (int ks = 0; ks < 2; ++ks) {
        __syncthreads();
        {
            const char* wrow = ws2 + (size_t)nrow0 * W2_ROWB + ks * 128;
            #pragma unroll
            for (int c = 0; c < 4; ++c) {
                int s = c * 4096 + wid * 1024 + lane * 16;
                int n = s >> 7, cb = s & 127;
                gload_lds16(wrow + (size_t)n * W2_ROWB + cb,
                            Bl + c * 4096 + wid * 1024);
            }
        }
        #pragma unroll
        for (int i = 0; i < 8; ++i) {
            int u = i * 256 + tid;
            int row = u >> 4;
            int k4 = (u & 15) << 2;
            f32x4 s4 = *(const f32x4*)(lat + (size_t)(m0 + row) * 128 + ks * 64 + k4);
            uint2 q; q.x = pk(s4.x, s4.y); q.y = pk(s4.z, s4.w);
            *(uint2*)(Al + (row << 7) + ((k4 << 1) ^ ((row & 7) << 4))) = q;
        }
        __syncthreads();

        #pragma unroll
        for (int b = 0; b < 2; ++b) {
            Frag af[4], bf[4];
            #pragma unroll
            for (int f = 0; f < 4; ++f) {
                int ra = wm + f * 16 + lp;  int xa = (ra & 7) << 4;
                af[f].d[0] = *(const unsigned long long*)(Al + (ra << 7) + ((b * 64 + lg * 8) ^ xa));
                af[f].d[1] = *(const unsigned long long*)(Al + (ra << 7) + ((b * 64 + 32 + lg * 8) ^ xa));
                int rb = wn + f * 16 + lp;  int xb = (rb & 7) << 4;
                bf[f].d[0] = *(const unsigned long long*)(Bl + (rb << 7) + ((b * 64 + lg * 8) ^ xb));
                bf[f].d[1] = *(const unsigned long long*)(Bl + (rb << 7) + ((b * 64 + 32 + lg * 8) ^ xb));
            }
            #pragma unroll
            for (int i = 0; i < 4; ++i)
                #pragma unroll
                for (int j = 0; j < 4; ++j)
                    acc[i][j] = __builtin_amdgcn_mfma_f32_16x16x32_f16(af[i].v, bf[j].v, acc[i][j], 0, 0, 0);
        }
    }

    #pragma unroll
    for (int i = 0; i < 4; ++i)
        #pragma unroll
        for (int j = 0; j < 4; ++j) {
            int row = m0 + wm + i * 16 + (lg << 2);
            int col = n0 + wn + j * 16 + lp;
            float* p = out + (size_t)row * 1024 + col;
            #pragma unroll
            for (int r = 0; r < 4; ++r) p[(size_t)r * 1024] = acc[i][j][r];
        }
}

// ============ merged fuse_a || gemm_kv (R9-identical) ============
__global__ __launch_bounds__(256, 2)
void fuse_kv(const float* __restrict__ S, const float* __restrict__ wsp,
             const float* __restrict__ whp, const float* __restrict__ whs,
             const float* __restrict__ wtg, char* __restrict__ a16,
             const float* __restrict__ lat, const char* __restrict__ ws2,
             float* __restrict__ outk, float* __restrict__ outv,
             int kvpg, int gsz) {
    __shared__ char lds[32768];
    int bid = blockIdx.x;
    int g = bid / gsz, slot = bid - g * gsz;
    if (slot < 17) {
        fuse_body((g * 17 + slot) * 256 + threadIdx.x, S, wsp, whp, whs, wtg, a16);
    } else {
        int idx = g * kvpg + (slot - 17);
        int mblk, nb;
        if (kvpg == 2) { int wg = (idx & 7) * 512 + (idx >> 3); mblk = wg >> 4; nb = wg & 15; }
        else           { int wg = (idx & 7) * 256 + (idx >> 3); mblk = wg >> 3; nb = wg & 7; }
        kv_body(mblk, nb, lat, ws2, outk, outv, lds);
    }
}

// v-half standalone (fallback path)
__global__ __launch_bounds__(256, 2)
void gemm_v(const float* __restrict__ lat, const char* __restrict__ ws2,
            float* __restrict__ outk, float* __restrict__ outv) {
    __shared__ char lds[32768];
    int idx = blockIdx.x;
    int wg = (idx & 7) * 256 + (idx >> 3);
    kv_body(wg >> 3, 8 + (wg & 7), lat, ws2, outk, outv, lds);
}

// ============ GEMM1: out = Af16 @ W_read^T — flat-staged counted pipeline =====
// BM=BN=256, BK=64, 8 waves, wave tile 128x64, 2 x 64 KB LDS dbuf.
// CHANGE vs R9: all 4 half-tile STAGEs of t+1 issue together at tile-t entry,
// so the vmcnt that waits on them lands 4 compute-phases (~1300 cyc) later —
// full HBM-latency cover (R9 staged half3 one phase before its wait: ~400 cyc
// exposed stall/tile). Compute phases have no LDS writes -> intra-tile barriers
// deleted: 2 barriers + 1 counted vmcnt(8) per tile (was 8 + 1).
__global__ __launch_bounds__(512, 2)
void gemm_read(const char* __restrict__ a16, const char* __restrict__ wws,
               float* __restrict__ out) {
    extern __shared__ char lds[];                // 131072 B

    int bid = blockIdx.x;
    int wg   = (bid & 7) * 64 + (bid >> 3);      // bijective XCD swizzle (512%8==0)
    int mblk = wg >> 2, nblk = wg & 3;
    int m0 = mblk << 8, n0 = nblk << 8;

    int tid = threadIdx.x;
    int lane = tid & 63, wid = tid >> 6;
    int wm = (wid >> 2) << 7, wn = (wid & 3) << 6;   // wave tile: 128x64
    int lp = lane & 15, lg = lane >> 4;

    int aoff = (wid >> 2) * 16384;               // wave's A-half region
    int boff = 32768 + (wn >> 7) * 16384;        // wave's B-half region
    int cb64 = wn & 64;                          // col base within B-half

    const char* srcH[4];
    srcH[0] = a16 + ((size_t)((m0 >> 7) * 17) << 14);
    srcH[1] = srcH[0] + (17 << 14);
    srcH[2] = wws + ((size_t)((n0 >> 7) * 17) << 14);
    srcH[3] = srcH[2] + (17 << 14);

    f32x4 acc[8][4] = {};
    Frag af[4], bf[4];

#define STAGE(T, H, DB) do {                                               \
        const char* s_ = srcH[H] + ((size_t)(T) << 14);                    \
        char* d_ = lds + (DB) + (H) * 16384;                               \
        gload_lds16(s_ + tid * 16, d_ + tid * 16);                         \
        gload_lds16(s_ + 8192 + tid * 16, d_ + 8192 + tid * 16);           \
    } while (0)

#define LOADA(MH, KH, BB) do {                                             \
        _Pragma("unroll")                                                  \
        for (int f = 0; f < 4; ++f) {                                      \
            int r_ = (MH) * 64 + f * 16 + lp;                              \
            af[f] = *(const Frag*)(lds + (BB) + aoff + (r_ << 7)           \
                     + ((((((KH) << 2) | lg) ^ (r_ & 7))) << 4));          \
        }                                                                  \
    } while (0)

#define LOADB(KH, BB) do {                                                 \
        _Pragma("unroll")                                                  \
        for (int g = 0; g < 4; ++g) {                                      \
            int c_ = cb64 + g * 16 + lp;                                   \
            bf[g] = *(const Frag*)(lds + (BB) + boff + (c_ << 7)           \
                     + ((((((KH) << 2) | lg) ^ (c_ & 7))) << 4));          \
        }                                                                  \
    } while (0)

#define MFMA16(MH) do {                                                    \
        __builtin_amdgcn_s_setprio(1);                                     \
        _Pragma("unroll")                                                  \
        for (int f = 0; f < 4; ++f)                                        \
            _Pragma("unroll")                                              \
            for (int g = 0; g < 4; ++g)                                    \
                acc[(MH) * 4 + f][g] = __builtin_amdgcn_mfma_f32_16x16x32_f16( \
                    af[f].v, bf[g].v, acc[(MH) * 4 + f][g], 0, 0, 0);      \
        __builtin_amdgcn_s_setprio(0);                                     \
    } while (0)

    // prologue: stage tile 0 fully into buf 0 (8 loads/thread outstanding)
    STAGE(0, 0, 0); STAGE(0, 1, 0); STAGE(0, 2, 0); STAGE(0, 3, 0);

    for (int t = 0; t < 17; ++t) {
        int BB = (t & 1) << 16;
        int NB = BB ^ 65536;
        // barrier #1: every wave finished tile t-1's compute -> NB free to fill
        __builtin_amdgcn_s_barrier();
        if (t < 16) {
            STAGE(t + 1, 0, NB); STAGE(t + 1, 1, NB);
            STAGE(t + 1, 2, NB); STAGE(t + 1, 3, NB);
            // own tile-t loads (issued one full tile ago) retired; t+1's 8 fly on
            asm volatile("s_waitcnt vmcnt(8)" ::: "memory");
        } else {
            asm volatile("s_waitcnt vmcnt(0)" ::: "memory");
        }
        // barrier #2: ALL threads' tile-t loads are visible in LDS
        __builtin_amdgcn_s_barrier();

        LOADB(0, BB); LOADA(0, 0, BB); MFMA16(0);
        LOADA(1, 0, BB);               MFMA16(1);
        LOADB(1, BB); LOADA(0, 1, BB); MFMA16(0);
        LOADA(1, 1, BB);               MFMA16(1);
    }

    // epilogue: C[row = m0+wm+i*16+lg*4+r][col = n0+wn+j*16+lp]
    #pragma unroll
    for (int i = 0; i < 8; ++i)
        #pragma unroll
        for (int j = 0; j < 4; ++j) {
            int row = m0 + wm + i * 16 + (lg << 2);
            int col = n0 + wn + j * 16 + lp;
            float* p = out + (size_t)row * 1024 + col;
            #pragma unroll
            for (int r = 0; r < 4; ++r) p[(size_t)r * 1024] = acc[i][j][r];
        }
#undef STAGE
#undef LOADA
#undef LOADB
#undef MFMA16
}

// ============ host ============
extern "C" void kernel_launch(void* const* d_in, const int* in_sizes, int n_in,
                              void* d_out, int out_size, void* d_ws, size_t ws_size,
                              hipStream_t stream) {
    const float* S   = (const float*)d_in[0];
    const float* wsp = (const float*)d_in[1];
    const float* whp = (const float*)d_in[2];
    const float* whs = (const float*)d_in[3];
    const float* wtg = (const float*)d_in[4];
    const float* Wr  = (const float*)d_in[5];
    // d_in[6] = cache: fully overwritten by latent -> dead input
    const float* lat = (const float*)d_in[7];
    const float* Wk  = (const float*)d_in[8];
    const float* Wv  = (const float*)d_in[9];
    float* out = (float*)d_out;
    char*  ws  = (char*)d_ws;

    float* outk = out + 33554432ull;
    float* outv = out + 67108864ull;

    static bool lds_init = false;
    if (!lds_init) {
        hipFuncSetAttribute(reinterpret_cast<const void*>(gemm_read),
                            hipFuncAttributeMaxDynamicSharedMemorySize, 131072);
        lds_init = true;
    }

    const size_t A16_WS_OFF = (size_t)WS2_OFF + WS2_SZ;   // 2,752,512
    const size_t ws_need = A16_WS_OFF + A16_SZ;           // ~74 MB

    hipLaunchKernelGGL(prep_w, dim3(1344), dim3(256), 0, stream, Wr, Wk, Wv, ws);

    if (ws_size >= ws_need) {
        // a16 in workspace: merge fuse_a with FULL kv (k and v), 3 launches
        char* a16 = ws + A16_WS_OFF;
        hipLaunchKernelGGL(fuse_kv, dim3(2048 * 19), dim3(256), 0, stream,
                           S, wsp, whp, whs, wtg, a16,
                           lat, ws + WS2_OFF, outk, outv, 2, 19);
        hipLaunchKernelGGL(gemm_read, dim3(512), dim3(512), 131072, stream,
                           a16, ws, out);
    } else {
        // a16 aliases outv: merge fuse_a with the k-half only; v after gemm_read
        char* a16 = (char*)outv;
        hipLaunchKernelGGL(fuse_kv, dim3(2048 * 18), dim3(256), 0, stream,
                           S, wsp, whp, whs, wtg, a16,
                           lat, ws + WS2_OFF, outk, outv, 1, 18);
        hipLaunchKernelGGL(gemm_read, dim3(512), dim3(512), 131072, stream,
                           a16, ws, out);
        hipLaunchKernelGGL(gemm_v, dim3(2048), dim3(256), 0, stream,
                           lat, ws + WS2_OFF, outk, outv);
    }
}

// Round 12
// 229.201 us; speedup vs baseline: 1.5623x; 1.0329x over previous
//
#include <hip/hip_runtime.h>

// ---------- types ----------
typedef __attribute__((ext_vector_type(8))) _Float16 half8;
typedef __attribute__((ext_vector_type(2))) __fp16 half2r;   // cvt_pkrtz return type
typedef __attribute__((ext_vector_type(4))) float f32x4;

#define AS1 __attribute__((address_space(1)))
#define AS3 __attribute__((address_space(3)))

union H2U { half2r h; unsigned int u; };
union Frag { half8 v; unsigned long long d[2]; };

__device__ __forceinline__ unsigned int pk(float a, float b) {
    H2U x; x.h = __builtin_amdgcn_cvt_pkrtz(a, b); return x.u;
}

__device__ __forceinline__ void gload_lds16(const void* g, void* l) {
    __builtin_amdgcn_global_load_lds((const AS1 unsigned int*)g,
                                     (AS3 unsigned int*)l, 16, 0, 0);
}

// ---------- problem constants ----------
// M = B*T = 32768, D_STATE = 1088, D_MODEL = 1024, D_LATENT = 128
// a16 / W1 layout: panel-tile 16 KB blocks at ((p*17 + t) << 14); within:
//   byte = (r<<7) + ((((kh<<2)|u) ^ (r&7)) << 4) + pos8   (R8-verified,
//   oct-conflict-free wave64 b128 frag reads; one MFMA frag = one 16-B slot)
#define WS2_OFF 2228224        // = 1024 rows * 2176 B  (W1 total size)
#define WS2_SZ  524288         // 2048 rows * 256 B
#define W2_ROWB 256            // kv weights: 2-slab 128-B layout
#define A16_SZ  71303168ull    // 32768 * 2176

// pick the fused-add source for 64-f32 slab ks (0..16)
__device__ __forceinline__ void pick_w(int ks, const float* wsp, const float* whp,
                                       const float* whs, const float* wtg,
                                       const float*& wbase, int& wstr, int& wko) {
    if (ks < 8)       { wbase = wsp; wstr = 512; wko = ks * 64; }
    else if (ks < 12) { wbase = whp; wstr = 256; wko = ks * 64 - 512; }
    else if (ks < 16) { wbase = whs; wstr = 256; wko = ks * 64 - 768; }
    else              { wbase = wtg; wstr = 64;  wko = 0; }
}

// packed-frag address within a 16-KB panel-tile block
__device__ __forceinline__ size_t pf_addr(int r, int kt) {
    int kh = kt >> 5, k32 = kt & 31;
    int u = (k32 & 15) >> 2, pos8 = (k32 >> 4) << 3;
    return ((size_t)r << 7) + ((size_t)((((kh << 2) | u) ^ (r & 7)) << 4)) + pos8;
}

// ============ prologue (dispatch 1): Wk|Wv -> f16 only ============
// (ws2 is read by kv blocks inside fuse_kv -> must be a PRIOR dispatch.
//  W_read prep moved into fuse_kv's grid tail: consumed only by gemm_read.)
__global__ __launch_bounds__(256) void prep_w(const float* __restrict__ Wk,
                                              const float* __restrict__ Wv,
                                              char* __restrict__ ws) {
    int j = blockIdx.x * 256 + threadIdx.x;      // 65536 units
    int r = j >> 5;                              // 0..2047
    int k = (j & 31) << 2;                       // 0..124
    const float* src = (r < 1024) ? (Wk + (size_t)r * 128 + k)
                                  : (Wv + (size_t)(r - 1024) * 128 + k);
    f32x4 w = *(const f32x4*)src;
    uint2 q; q.x = pk(w.x, w.y); q.y = pk(w.z, w.w);
    size_t off = WS2_OFF + (size_t)r * W2_ROWB + ((k >> 6) << 7)
               + (((k & 63) << 1) ^ ((r & 7) << 4));
    *(uint2*)(ws + off) = q;
}

// ---------- fuse_a body (R9-identical) ----------
__device__ __forceinline__
void fuse_body(int u, const float* __restrict__ S, const float* __restrict__ wsp,
               const float* __restrict__ whp, const float* __restrict__ whs,
               const float* __restrict__ wtg, char* __restrict__ a16) {
    int row = u / 272;
    int rem = u % 272;
    int ks = rem >> 4;
    int k4 = (rem & 15) << 2;

    const float* wbase; int wstr, wko;
    pick_w(ks, wsp, whp, whs, wtg, wbase, wstr, wko);

    f32x4 s4 = *(const f32x4*)(S + (size_t)row * 1088 + ks * 64 + k4);
    f32x4 w4 = *(const f32x4*)(wbase + (size_t)row * wstr + wko + k4);
    uint2 q; q.x = pk(s4.x + w4.x, s4.y + w4.y);
             q.y = pk(s4.z + w4.z, s4.w + w4.w);
    size_t off = ((size_t)((row >> 7) * 17 + ks) << 14) + pf_addr(row & 127, k4);
    *(uint2*)(a16 + off) = q;
}

// ---------- kv body (R9-identical) ----------
__device__ __forceinline__
void kv_body(int mblk, int nb, const float* __restrict__ lat,
             const char* __restrict__ ws2, float* __restrict__ outk,
             float* __restrict__ outv, char* lds) {
    char* Al = lds;
    char* Bl = lds + 16384;

    int m0 = mblk << 7;
    int nrow0 = nb << 7;
    float* out = (nb < 8) ? outk : outv;
    int n0 = (nb & 7) << 7;

    int tid = threadIdx.x;
    int lane = tid & 63, wid = tid >> 6;
    int wm = (wid >> 1) << 6, wn = (wid & 1) << 6;
    int lp = lane & 15, lg = lane >> 4;

    f32x4 acc[4][4] = {};

    for (int ks = 0; ks < 2; ++ks) {
        __syncthreads();
        {
            const char* wrow = ws2 + (size_t)nrow0 * W2_ROWB + ks * 128;
            #pragma unroll
            for (int c = 0; c < 4; ++c) {
                int s = c * 4096 + wid * 1024 + lane * 16;
                int n = s >> 7, cb = s & 127;
                gload_lds16(wrow + (size_t)n * W2_ROWB + cb,
                            Bl + c * 4096 + wid * 1024);
            }
        }
        #pragma unroll
        for (int i = 0; i < 8; ++i) {
            int u = i * 256 + tid;
            int row = u >> 4;
            int k4 = (u & 15) << 2;
            f32x4 s4 = *(const f32x4*)(lat + (size_t)(m0 + row) * 128 + ks * 64 + k4);
            uint2 q; q.x = pk(s4.x, s4.y); q.y = pk(s4.z, s4.w);
            *(uint2*)(Al + (row << 7) + ((k4 << 1) ^ ((row & 7) << 4))) = q;
        }
        __syncthreads();

        #pragma unroll
        for (int b = 0; b < 2; ++b) {
            Frag af[4], bf[4];
            #pragma unroll
            for (int f = 0; f < 4; ++f) {
                int ra = wm + f * 16 + lp;  int xa = (ra & 7) << 4;
                af[f].d[0] = *(const unsigned long long*)(Al + (ra << 7) + ((b * 64 + lg * 8) ^ xa));
                af[f].d[1] = *(const unsigned long long*)(Al + (ra << 7) + ((b * 64 + 32 + lg * 8) ^ xa));
                int rb = wn + f * 16 + lp;  int xb = (rb & 7) << 4;
                bf[f].d[0] = *(const unsigned long long*)(Bl + (rb << 7) + ((b * 64 + lg * 8) ^ xb));
                bf[f].d[1] = *(const unsigned long long*)(Bl + (rb << 7) + ((b * 64 + 32 + lg * 8) ^ xb));
            }
            #pragma unroll
            for (int i = 0; i < 4; ++i)
                #pragma unroll
                for (int j = 0; j < 4; ++j)
                    acc[i][j] = __builtin_amdgcn_mfma_f32_16x16x32_f16(af[i].v, bf[j].v, acc[i][j], 0, 0, 0);
        }
    }

    #pragma unroll
    for (int i = 0; i < 4; ++i)
        #pragma unroll
        for (int j = 0; j < 4; ++j) {
            int row = m0 + wm + i * 16 + (lg << 2);
            int col = n0 + wn + j * 16 + lp;
            float* p = out + (size_t)row * 1024 + col;
            #pragma unroll
            for (int r = 0; r < 4; ++r) p[(size_t)r * 1024] = acc[i][j][r];
        }
}

// ============ merged fuse_a || gemm_kv || W1-prep ============
// Groups of gsz blocks: 17 fuse-role + kvpg kv-role (kv spread uniformly).
// Tail (+1088 blocks): W_read -> f16 packed-frag (consumed only by gemm_read,
// a LATER dispatch -> legal in this one). launch_bounds(256,3): 3 blocks/CU
// (12 waves) for the HBM-bound mix (was 2; VGPR cap ~170 fits kv's ~116).
__global__ __launch_bounds__(256, 3)
void fuse_kv(const float* __restrict__ S, const float* __restrict__ wsp,
             const float* __restrict__ whp, const float* __restrict__ whs,
             const float* __restrict__ wtg, char* __restrict__ a16,
             const float* __restrict__ lat, const char* __restrict__ ws2,
             float* __restrict__ outk, float* __restrict__ outv,
             const float* __restrict__ Wr, char* __restrict__ ws,
             int kvpg, int gsz, int nmain) {
    __shared__ char lds[32768];
    int bid = blockIdx.x;
    if (bid >= nmain) {                          // ---- W1-prep tail role
        int id = (bid - nmain) * 256 + threadIdx.x;
        int n = id / 272;
        int k = (id % 272) * 4;
        f32x4 w = *(const f32x4*)(Wr + (size_t)n * 1088 + k);
        uint2 q; q.x = pk(w.x, w.y); q.y = pk(w.z, w.w);
        int t = k >> 6;
        size_t off = ((size_t)((n >> 7) * 17 + t) << 14) + pf_addr(n & 127, k & 63);
        *(uint2*)(ws + off) = q;
        return;
    }
    int g = bid / gsz, slot = bid - g * gsz;
    if (slot < 17) {
        fuse_body((g * 17 + slot) * 256 + threadIdx.x, S, wsp, whp, whs, wtg, a16);
    } else {
        int idx = g * kvpg + (slot - 17);
        int mblk, nb;
        if (kvpg == 2) { int wg = (idx & 7) * 512 + (idx >> 3); mblk = wg >> 4; nb = wg & 15; }
        else           { int wg = (idx & 7) * 256 + (idx >> 3); mblk = wg >> 3; nb = wg & 7; }
        kv_body(mblk, nb, lat, ws2, outk, outv, lds);
    }
}

// v-half standalone (fallback path)
__global__ __launch_bounds__(256, 3)
void gemm_v(const float* __restrict__ lat, const char* __restrict__ ws2,
            float* __restrict__ outk, float* __restrict__ outv) {
    __shared__ char lds[32768];
    int idx = blockIdx.x;
    int wg = (idx & 7) * 256 + (idx >> 3);
    kv_body(wg >> 3, 8 + (wg & 7), lat, ws2, outk, outv, lds);
}

// ============ GEMM1: out = Af16 @ W_read^T — R9 champion 4-phase schedule =====
// BM=BN=256, BK=64, 8 waves (2M x 4N), wave tile 128x64, 2 x 64 KB LDS dbuf.
// Per phase: pre-barrier ds_read of one reg subtile + stage one half-tile of
// tile t+1 (2 gload_lds) -> barrier -> 16 MFMA (setprio) -> barrier.
// vmcnt(2) ONCE per tile at phase 0 (counted, never drained in loop — T4).
__global__ __launch_bounds__(512, 2)
void gemm_read(const char* __restrict__ a16, const char* __restrict__ wws,
               float* __restrict__ out) {
    extern __shared__ char lds[];                // 131072 B

    int bid = blockIdx.x;
    int wg   = (bid & 7) * 64 + (bid >> 3);      // bijective XCD swizzle (512%8==0)
    int mblk = wg >> 2, nblk = wg & 3;
    int m0 = mblk << 8, n0 = nblk << 8;

    int tid = threadIdx.x;
    int lane = tid & 63, wid = tid >> 6;
    int wm = (wid >> 2) << 7, wn = (wid & 3) << 6;   // wave tile: 128x64
    int lp = lane & 15, lg = lane >> 4;

    int aoff = (wid >> 2) * 16384;               // wave's A-half region
    int boff = 32768 + (wn >> 7) * 16384;        // wave's B-half region
    int cb64 = wn & 64;                          // col base within B-half

    const char* srcH[4];
    srcH[0] = a16 + ((size_t)((m0 >> 7) * 17) << 14);
    srcH[1] = srcH[0] + (17 << 14);
    srcH[2] = wws + ((size_t)((n0 >> 7) * 17) << 14);
    srcH[3] = srcH[2] + (17 << 14);

    f32x4 acc[8][4] = {};
    Frag af[4], bf[4];

#define STAGE(T, H, DB) do {                                               \
        const char* s_ = srcH[H] + ((size_t)(T) << 14);                    \
        char* d_ = lds + (DB) + (H) * 16384;                               \
        gload_lds16(s_ + tid * 16, d_ + tid * 16);                         \
        gload_lds16(s_ + 8192 + tid * 16, d_ + 8192 + tid * 16);           \
    } while (0)

#define LOADA(MH, KH, BB) do {                                             \
        _Pragma("unroll")                                                  \
        for (int f = 0; f < 4; ++f) {                                      \
            int r_ = (MH) * 64 + f * 16 + lp;                              \
            af[f] = *(const Frag*)(lds + (BB) + aoff + (r_ << 7)           \
                     + ((((((KH) << 2) | lg) ^ (r_ & 7))) << 4));          \
        }                                                                  \
    } while (0)

#define LOADB(KH, BB) do {                                                 \
        _Pragma("unroll")                                                  \
        for (int g = 0; g < 4; ++g) {                                      \
            int c_ = cb64 + g * 16 + lp;                                   \
            bf[g] = *(const Frag*)(lds + (BB) + boff + (c_ << 7)           \
                     + ((((((KH) << 2) | lg) ^ (c_ & 7))) << 4));          \
        }                                                                  \
    } while (0)

#define MFMA16(MH) do {                                                    \
        __builtin_amdgcn_s_setprio(1);                                     \
        _Pragma("unroll")                                                  \
        for (int f = 0; f < 4; ++f)                                        \
            _Pragma("unroll")                                              \
            for (int g = 0; g < 4; ++g)                                    \
                acc[(MH) * 4 + f][g] = __builtin_amdgcn_mfma_f32_16x16x32_f16( \
                    af[f].v, bf[g].v, acc[(MH) * 4 + f][g], 0, 0, 0);      \
        __builtin_amdgcn_s_setprio(0);                                     \
    } while (0)

    // prologue: stage tile 0 fully into buf 0 (8 loads/thread outstanding)
    STAGE(0, 0, 0); STAGE(0, 1, 0); STAGE(0, 2, 0); STAGE(0, 3, 0);

    for (int t = 0; t < 16; ++t) {
        int BB = (t & 1) << 16;
        int NB = BB ^ 65536;
        // ---- phase 0 (mh=0, kh=0)
        STAGE(t + 1, 0, NB);
        asm volatile("s_waitcnt vmcnt(2)" ::: "memory");  // tile t landed; 2 fly on
        __builtin_amdgcn_s_barrier();
        LOADB(0, BB); LOADA(0, 0, BB);
        MFMA16(0);
        __builtin_amdgcn_s_barrier();
        // ---- phase 1 (mh=1, kh=0): ds_read pre-barrier (data resident)
        LOADA(1, 0, BB);
        STAGE(t + 1, 1, NB);
        __builtin_amdgcn_s_barrier();
        MFMA16(1);
        __builtin_amdgcn_s_barrier();
        // ---- phase 2 (mh=0, kh=1)
        LOADB(1, BB); LOADA(0, 1, BB);
        STAGE(t + 1, 2, NB);
        __builtin_amdgcn_s_barrier();
        MFMA16(0);
        __builtin_amdgcn_s_barrier();
        // ---- phase 3 (mh=1, kh=1)
        LOADA(1, 1, BB);
        STAGE(t + 1, 3, NB);
        __builtin_amdgcn_s_barrier();
        MFMA16(1);
        __builtin_amdgcn_s_barrier();
    }
    // ---- tail: tile 16 (in buf 0), nothing left to stage
    {
        const int BB = 0;
        asm volatile("s_waitcnt vmcnt(0)" ::: "memory");
        __builtin_amdgcn_s_barrier();
        LOADB(0, BB); LOADA(0, 0, BB); MFMA16(0);
        __builtin_amdgcn_s_barrier();
        LOADA(1, 0, BB); MFMA16(1);
        __builtin_amdgcn_s_barrier();
        LOADB(1, BB); LOADA(0, 1, BB); MFMA16(0);
        __builtin_amdgcn_s_barrier();
        LOADA(1, 1, BB); MFMA16(1);
    }

    // epilogue: C[row = m0+wm+i*16+lg*4+r][col = n0+wn+j*16+lp]
    #pragma unroll
    for (int i = 0; i < 8; ++i)
        #pragma unroll
        for (int j = 0; j < 4; ++j) {
            int row = m0 + wm + i * 16 + (lg << 2);
            int col = n0 + wn + j * 16 + lp;
            float* p = out + (size_t)row * 1024 + col;
            #pragma unroll
            for (int r = 0; r < 4; ++r) p[(size_t)r * 1024] = acc[i][j][r];
        }
#undef STAGE
#undef LOADA
#undef LOADB
#undef MFMA16
}

// ============ host ============
extern "C" void kernel_launch(void* const* d_in, const int* in_sizes, int n_in,
                              void* d_out, int out_size, void* d_ws, size_t ws_size,
                              hipStream_t stream) {
    const float* S   = (const float*)d_in[0];
    const float* wsp = (const float*)d_in[1];
    const float* whp = (const float*)d_in[2];
    const float* whs = (const float*)d_in[3];
    const float* wtg = (const float*)d_in[4];
    const float* Wr  = (const float*)d_in[5];
    // d_in[6] = cache: fully overwritten by latent -> dead input
    const float* lat = (const float*)d_in[7];
    const float* Wk  = (const float*)d_in[8];
    const float* Wv  = (const float*)d_in[9];
    float* out = (float*)d_out;
    char*  ws  = (char*)d_ws;

    float* outk = out + 33554432ull;
    float* outv = out + 67108864ull;

    static bool lds_init = false;
    if (!lds_init) {
        hipFuncSetAttribute(reinterpret_cast<const void*>(gemm_read),
                            hipFuncAttributeMaxDynamicSharedMemorySize, 131072);
        lds_init = true;
    }

    const size_t A16_WS_OFF = (size_t)WS2_OFF + WS2_SZ;   // 2,752,512
    const size_t ws_need = A16_WS_OFF + A16_SZ;           // ~74 MB

    // dispatch 1: ws2 (Wk|Wv) prep only — kv blocks in dispatch 2 read it
    hipLaunchKernelGGL(prep_w, dim3(256), dim3(256), 0, stream, Wk, Wv, ws);

    if (ws_size >= ws_need) {
        // a16 in workspace: fuse || FULL kv (+W1-prep tail), then gemm_read
        char* a16 = ws + A16_WS_OFF;
        int nmain = 2048 * 19;
        hipLaunchKernelGGL(fuse_kv, dim3(nmain + 1088), dim3(256), 0, stream,
                           S, wsp, whp, whs, wtg, a16,
                           lat, ws + WS2_OFF, outk, outv, Wr, ws, 2, 19, nmain);
        hipLaunchKernelGGL(gemm_read, dim3(512), dim3(512), 131072, stream,
                           a16, ws, out);
    } else {
        // a16 aliases outv: fuse || k-half (+W1-prep tail); v after gemm_read
        char* a16 = (char*)outv;
        int nmain = 2048 * 18;
        hipLaunchKernelGGL(fuse_kv, dim3(nmain + 1088), dim3(256), 0, stream,
                           S, wsp, whp, whs, wtg, a16,
                           lat, ws + WS2_OFF, outk, outv, Wr, ws, 1, 18, nmain);
        hipLaunchKernelGGL(gemm_read, dim3(512), dim3(512), 131072, stream,
                           a16, ws, out);
        hipLaunchKernelGGL(gemm_v, dim3(2048), dim3(256), 0, stream,
                           lat, ws + WS2_OFF, outk, outv);
    }
}